// Round 11
// baseline (185.003 us; speedup 1.0000x reference)
//
#include <hip/hip_runtime.h>

#define N_TOK 65536
#define DIM   64
#define K_EMB 512
#define BT    128     // tokens per block
#define NTHR  1024    // 16 waves: waves 0-7 sweep codes [0,256), 8-15 [256,512)
#define MARGIN 0.125f // > 2x worst-case f16-split sq error (~0.062)

typedef _Float16 half8 __attribute__((ext_vector_type(8)));
typedef _Float16 half4 __attribute__((ext_vector_type(4)));
typedef float    f32x4 __attribute__((ext_vector_type(4)));

// d_out layout (fp32, concatenated in return order):
//   [0)         encodings_ste  N_TOK*DIM   = 4194304
//   [4194304)   idx (as float) N_TOK       = 65536
//   [4259840)   sq_distances   K_EMB*N_TOK = 33554432
//   [37814272)  loss           1
//
// d_ws layout: [0) enorm 512 f32 (2 KB) | [2048) eh f16 codebook [512][64] (64 KB)
//
// R11: in-block code-split for 32 waves/CU. R10 showed 2 blocks/CU at 8 waves
// each = same 16 waves/CU as R9 (+4us from overlap only). sqw's measured 35.6us
// for the full sq traffic ran at 32 waves/CU. Here the 16 waves of each block
// split the CODE dim (half-codebook each, 16 kt steps), same 128 tokens; both
// halves push candidates into the SAME LDS cand/ccnt arrays (max 6 <= cap 8, no
// eviction possible); exact fp32 repair picks lexicographic-min (sq,k) ->
// order-independent, tie semantics intact. Margin safety per half: the half
// holding the true argmin has local mstar <= approx(k*), so its thr admits k*
// by the same eps<MARGIN argument; the other half only adds repair-filtered
// extras.

// Prep: f16 codebook + fp32 e-norms into ws; zero loss. 32x256 threads.
__global__ void vq_prep(const float* __restrict__ emb,
                        float* __restrict__ enorm,
                        _Float16* __restrict__ eh,
                        float* __restrict__ loss) {
    const int gid = blockIdx.x * blockDim.x + threadIdx.x;   // 8192 threads
    {
        float4 v = ((const float4*)emb)[gid];
        half4 h = { (_Float16)v.x, (_Float16)v.y, (_Float16)v.z, (_Float16)v.w };
        ((half4*)eh)[gid] = h;
    }
    if (gid == 0) *loss = 0.0f;
    if (gid < K_EMB) {
        const float4* e4 = (const float4*)(emb + (size_t)gid * DIM);
        float s = 0.0f;
        #pragma unroll
        for (int i = 0; i < 16; ++i) {
            float4 v = e4[i];
            s += v.x * v.x + v.y * v.y + v.z * v.z + v.w * v.w;
        }
        enorm[gid] = s;
    }
}

__global__ __launch_bounds__(NTHR, 4) void vq_main(
    const float* __restrict__ x,      // [N_TOK, DIM]
    const float* __restrict__ emb,    // [K_EMB, DIM] fp32 (exact repair + epilogue)
    const float* __restrict__ enorm,  // [K_EMB] fp32 |e|^2
    const _Float16* __restrict__ eh,  // [K_EMB][DIM] f16 codebook
    float* __restrict__ out_enc,
    float* __restrict__ out_idx,
    float* __restrict__ out_sq,
    float* __restrict__ out_loss)
{
    // 64K + 2K + 0.5K + 0.5K + 4K + 0.5K + 64B = ~71.6 KB -> 2 blocks/CU
    __shared__ _Float16 eh_s[K_EMB * DIM];   // XOR-swizzled: byte ^= ((row&7)<<4)
    __shared__ float en_s[K_EMB];
    __shared__ float xn_s[BT];
    __shared__ int   ccnt[BT];
    __shared__ int   cand[BT * 8];
    __shared__ int   besti[BT];
    __shared__ float lsum[16];

    const int tid  = threadIdx.x;
    // bijective XCD-contiguous chunk swizzle (512 blocks, 8 XCDs, 64 chunks/XCD)
    const int bid   = blockIdx.x;
    const int chunk = ((bid & 7) << 6) | (bid >> 3);
    const int n0    = chunk * BT;
    const int lane = tid & 63;
    const int w    = tid >> 6;      // wave id 0..15
    const int g    = w >> 3;        // code-half group: 0 -> codes [0,256), 1 -> [256,512)
    const int ws   = w & 7;         // wave-in-group = 16-token tile (0..7)
    const int kbase = g << 8;       // 0 or 256
    const int lr   = lane & 15;
    const int quad = lane >> 4;
    const int tok  = ws * 16 + lr;  // 0..127

    // ====== phase 0a: issue codebook loads early (64 B/thread, 64 KB/block) ======
    f32x4 st[4];
    {
        const f32x4* gptr = (const f32x4*)eh;   // 4096 x 16B chunks
        #pragma unroll
        for (int r = 0; r < 4; ++r) st[r] = gptr[r * NTHR + tid];
    }

    // ====== phase 0b: small staging (latency of 0a hides under this) ======
    if (tid < 128) ((float4*)en_s)[tid] = ((const float4*)enorm)[tid];
    if (tid < BT) {
        ccnt[tid] = 0;
        // xn with the exact quad-pairwise formula (bit-matched to the repair path).
        const float4* xr = (const float4*)(x + (size_t)(n0 + tid) * DIM);
        float x0 = 0.f, x1 = 0.f, x2 = 0.f, x3 = 0.f;
        #pragma unroll
        for (int c = 0; c < 16; ++c) {
            float4 v = xr[c];
            x0 = fmaf(v.x, v.x, x0);
            x1 = fmaf(v.y, v.y, x1);
            x2 = fmaf(v.z, v.z, x2);
            x3 = fmaf(v.w, v.w, x3);
        }
        xn_s[tid] = (x0 + x1) + (x2 + x3);
    }

    // ---- B-frags straight from global: lane owns X[tok][quad*8..+8] and [+32..] ----
    // (both wave-groups load the same 128 rows; duplicate loads are L2 hits)
    half8 bxh0, bxl0, bxh1, bxl1;
    {
        const float4* xrow = (const float4*)(x + (size_t)(n0 + tok) * DIM);
        float4 v0 = xrow[quad * 2];
        float4 v1 = xrow[quad * 2 + 1];
        float4 v2 = xrow[8 + quad * 2];
        float4 v3 = xrow[8 + quad * 2 + 1];
        float f0[8] = { v0.x, v0.y, v0.z, v0.w, v1.x, v1.y, v1.z, v1.w };
        float f1[8] = { v2.x, v2.y, v2.z, v2.w, v3.x, v3.y, v3.z, v3.w };
        #pragma unroll
        for (int i = 0; i < 8; ++i) {
            _Float16 h = (_Float16)f0[i];
            bxh0[i] = h; bxl0[i] = (_Float16)(f0[i] - (float)h);
            _Float16 gg = (_Float16)f1[i];
            bxh1[i] = gg; bxl1[i] = (_Float16)(f1[i] - (float)gg);
        }
    }

    // ====== phase 0c: swizzled ds_write of the codebook ======
    // lds[row*128 + (col ^ ((row&7)<<4))] = eh[row*128 + col]  (involution)
    {
        #pragma unroll
        for (int r = 0; r < 4; ++r) {
            const unsigned L = (unsigned)(r * NTHR + tid) * 16u;
            const unsigned d = (L & ~127u) | ((L & 127u) ^ (((L >> 7) & 7u) << 4));
            *(f32x4*)((char*)eh_s + d) = st[r];
        }
    }
    __syncthreads();
    const float xnl = xn_s[tok];

    // ================= phase 1: MFMA sweep (A from swizzled LDS) =================
    // Group g sweeps codes [kbase, kbase+256) in 16 kt steps.
    // A frag: lane holds E[code = kbase + kt*16 + lr][k = quad*8 + j]
    // C frag: lane reg holds D[code = kbase + kt*16 + quad*4 + reg][token = tok]
    // row&7 == lr&7 (kbase, kt*16 both ≡ 0 mod 8) -> same swizzle as before.
    const unsigned sw = (unsigned)(lr & 7) << 4;
    const char* abase = (const char*)eh_s + (unsigned)(kbase + lr) * 128u;
    const unsigned c0 = ((unsigned)(quad * 16)) ^ sw;
    const unsigned c1 = c0 ^ 64u;   // == ((quad*16+64) ^ sw)

    float m1 = 3.4e38f, m2 = 3.4e38f, m3 = 3.4e38f;
    int   i1 = 0, i2 = 0, i3 = 0;

    half8 a0 = *(const half8*)(abase + c0);
    half8 a1 = *(const half8*)(abase + c1);

    for (int kt = 0; kt < 16; ++kt) {
        // prefetch next tile's A-frags from LDS (clamped re-read of last tile)
        const int ktn = kt < 15 ? kt + 1 : 15;
        half8 na0 = *(const half8*)(abase + (unsigned)ktn * 2048u + c0);
        half8 na1 = *(const half8*)(abase + (unsigned)ktn * 2048u + c1);

        f32x4 acc = { 0.f, 0.f, 0.f, 0.f };
        acc = __builtin_amdgcn_mfma_f32_16x16x32_f16(a0, bxh0, acc, 0, 0, 0);
        acc = __builtin_amdgcn_mfma_f32_16x16x32_f16(a1, bxh1, acc, 0, 0, 0);
        acc = __builtin_amdgcn_mfma_f32_16x16x32_f16(a0, bxl0, acc, 0, 0, 0);
        acc = __builtin_amdgcn_mfma_f32_16x16x32_f16(a1, bxl1, acc, 0, 0, 0);

        const f32x4 e4 = *(const f32x4*)&en_s[kbase + kt * 16 + quad * 4];
        #pragma unroll
        for (int reg = 0; reg < 4; ++reg) {
            const int   ki = kbase + kt * 16 + quad * 4 + reg;
            const float sq = (xnl + e4[reg]) - 2.0f * acc[reg];
            out_sq[(size_t)ki * N_TOK + n0 + tok] = sq;   // free-flow store
            // 3-deep running min; ascending ki + strict < keeps first occurrence.
            if (sq < m3) {
                if (sq < m2) {
                    if (sq < m1) { m3 = m2; i3 = i2; m2 = m1; i2 = i1; m1 = sq; i1 = ki; }
                    else         { m3 = m2; i3 = i2; m2 = sq; i2 = ki; }
                } else           { m3 = sq; i3 = ki; }
            }
        }
        a0 = na0; a1 = na1;
    }

    // ============ phase 2: per-half candidates + exact fp32 repair ============
    // mstar is per-wave (this half's min for this token); per-half thr is safe:
    // the half holding the true argmin admits it (eps < MARGIN), extras filtered.
    float mstar = m1;
    mstar = fminf(mstar, __shfl_xor(mstar, 16, 64));
    mstar = fminf(mstar, __shfl_xor(mstar, 32, 64));
    const float thr = mstar + MARGIN;
    if (m1 <= thr) { int p = atomicAdd(&ccnt[tok], 1); if (p < 8) cand[tok * 8 + p] = i1; }
    if (m2 <= thr) { int p = atomicAdd(&ccnt[tok], 1); if (p < 8) cand[tok * 8 + p] = i2; }
    if (m3 <= thr) { int p = atomicAdd(&ccnt[tok], 1); if (p < 8) cand[tok * 8 + p] = i3; }
    __syncthreads();

    if (tid < BT) {
        const int cnt = min(ccnt[tid], 8);   // max 6 (3-deep x 2 halves)
        float bv = 3.4e38f;
        int   bi = 0x7fffffff;
        const float4* xr = (const float4*)(x + (size_t)(n0 + tid) * DIM);
        for (int c = 0; c < cnt; ++c) {
            const int k = cand[tid * 8 + c];
            const float4* ep = (const float4*)(emb + (size_t)k * DIM);
            // exact fp32 recompute, bit-identical to the passing arithmetic
            float d0 = 0.f, d1 = 0.f, d2 = 0.f, d3 = 0.f;
            #pragma unroll
            for (int j = 0; j < 16; ++j) {
                float4 xv = xr[j], ev = ep[j];
                d0 = fmaf(ev.x, xv.x, d0);
                d1 = fmaf(ev.y, xv.y, d1);
                d2 = fmaf(ev.z, xv.z, d2);
                d3 = fmaf(ev.w, xv.w, d3);
            }
            const float dot = (d0 + d1) + (d2 + d3);
            const float sq  = (xn_s[tid] + en_s[k]) - 2.0f * dot;
            // lexicographic (sq, k) min: order-independent across halves
            if (sq < bv || (sq == bv && k < bi)) { bv = sq; bi = k; }
        }
        besti[tid] = bi;
        out_idx[n0 + tid] = (float)bi;   // <= 511: exact in fp32
    }
    __syncthreads();

    // ================= phase 3: enc/ste + loss =================
    float lp = 0.0f;
    {
        const int c = (tid & 15) * 4;
        const int r = tid >> 4;          // 0..63
        #pragma unroll
        for (int p = 0; p < 2; ++p) {
            const int rr = r + 64 * p;   // 0..127
            const int bi = besti[rr];
            float4 e  = *(const float4*)&emb[(size_t)bi * DIM + c];
            *(float4*)&out_enc[(size_t)(n0 + rr) * DIM + c] = e;
            float4 xv = *(const float4*)&x[(size_t)(n0 + rr) * DIM + c];
            const float d0 = e.x - xv.x, d1 = e.y - xv.y, d2 = e.z - xv.z, d3 = e.w - xv.w;
            lp += d0 * d0 + d1 * d1 + d2 * d2 + d3 * d3;
        }
    }
    #pragma unroll
    for (int off = 32; off > 0; off >>= 1) lp += __shfl_down(lp, off, 64);
    // ONE device atomic per block (512 total)
    if (lane == 0) lsum[w] = lp;
    __syncthreads();
    if (tid == 0) {
        float s = 0.0f;
        #pragma unroll
        for (int i = 0; i < 16; ++i) s += lsum[i];
        atomicAdd(out_loss, s * (1.25f / 4194304.0f));  // (1+beta)*mean, beta=0.25
    }
}

extern "C" void kernel_launch(void* const* d_in, const int* in_sizes, int n_in,
                              void* d_out, int out_size, void* d_ws, size_t ws_size,
                              hipStream_t stream) {
    const float* x   = (const float*)d_in[0];
    const float* emb = (const float*)d_in[1];
    float* out       = (float*)d_out;
    float* enorm     = (float*)d_ws;                       // 512 f32
    _Float16* eh     = (_Float16*)((char*)d_ws + 2048);    // 512*64 f16 (64 KB)

    float* out_enc  = out;                // 4194304
    float* out_idx  = out + 4194304;      // 65536
    float* out_sq   = out + 4259840;      // 33554432
    float* out_loss = out + 37814272;     // 1

    vq_prep<<<32, 256, 0, stream>>>(emb, enorm, eh, out_loss);
    vq_main<<<N_TOK / BT, NTHR, 0, stream>>>(x, emb, enorm, eh,
                                             out_enc, out_idx, out_sq, out_loss);
}